// Round 1
// baseline (2884.886 us; speedup 1.0000x reference)
//
#include <hip/hip_runtime.h>

#define B_  4
#define C_  256
#define C8_ 32
#define N_  4096   // H*W = 64*64

// y[b,o,n] = sum_c W[o,c] * x[b,c,n]
// grid(N/256, OutC/16, B), block 256. 16 out-channels per block amortizes x reads.
__global__ __launch_bounds__(256) void proj_kernel(
    const float* __restrict__ W, const float* __restrict__ x,
    float* __restrict__ y, int outC)
{
    int n  = blockIdx.x * 256 + threadIdx.x;
    int o0 = blockIdx.y * 16;
    int b  = blockIdx.z;
    const float* xb = x + (size_t)b * C_ * N_;
    float acc[16];
#pragma unroll
    for (int k = 0; k < 16; ++k) acc[k] = 0.f;
    for (int c = 0; c < C_; ++c) {
        float xv = xb[c * N_ + n];
#pragma unroll
        for (int k = 0; k < 16; ++k)
            acc[k] += W[(o0 + k) * C_ + c] * xv;   // W index wave-uniform -> s_load
    }
#pragma unroll
    for (int k = 0; k < 16; ++k)
        y[((size_t)b * outC + o0 + k) * N_ + n] = acc[k];
}

// scores[i,j] = sum_{c<32} f[c,i] * g[c,j]  (one batch)
// grid(N/256 [j], N/16 [i]), block 256
__global__ __launch_bounds__(256) void scores_kernel(
    const float* __restrict__ f, const float* __restrict__ g,
    float* __restrict__ s)
{
    int j  = blockIdx.x * 256 + threadIdx.x;
    int i0 = blockIdx.y * 16;
    float acc[16];
#pragma unroll
    for (int k = 0; k < 16; ++k) acc[k] = 0.f;
    for (int c = 0; c < C8_; ++c) {
        float gv = g[c * N_ + j];                  // coalesced
#pragma unroll
        for (int k = 0; k < 16; ++k)
            acc[k] += f[c * N_ + i0 + k] * gv;     // uniform -> scalar loads
    }
#pragma unroll
    for (int k = 0; k < 16; ++k)
        s[(size_t)(i0 + k) * N_ + j] = acc[k];
}

// column max over i for each j. grid(N/64), block 256 (64 cols x 4-way i split)
__global__ __launch_bounds__(256) void colmax_kernel(
    const float* __restrict__ s, float* __restrict__ cmax)
{
    int jj = threadIdx.x & 63, is = threadIdx.x >> 6;
    int j  = blockIdx.x * 64 + jj;
    float m = -1e30f;
    for (int i = is; i < N_; i += 4)
        m = fmaxf(m, s[(size_t)i * N_ + j]);
    __shared__ float red[4][64];
    red[is][jj] = m;
    __syncthreads();
    if (is == 0) {
        m = fmaxf(fmaxf(red[0][jj], red[1][jj]), fmaxf(red[2][jj], red[3][jj]));
        cmax[j] = m;
    }
}

// overwrite s with exp(s - colmax) and write column sums. grid(N/64), block 256
__global__ __launch_bounds__(256) void expsum_kernel(
    float* __restrict__ s, const float* __restrict__ cmax,
    float* __restrict__ csum)
{
    int jj = threadIdx.x & 63, is = threadIdx.x >> 6;
    int j  = blockIdx.x * 64 + jj;
    float m = cmax[j];
    float sum = 0.f;
    for (int i = is; i < N_; i += 4) {
        size_t idx = (size_t)i * N_ + j;
        float e = __expf(s[idx] - m);
        s[idx] = e;
        sum += e;
    }
    __shared__ float red[4][64];
    red[is][jj] = sum;
    __syncthreads();
    if (is == 0) {
        csum[j] = red[0][jj] + red[1][jj] + red[2][jj] + red[3][jj];
    }
}

// out[c,j] = gamma * (sum_i hv[c,i]*se[i,j]) / csum[j] + x[c,j]  (one batch)
// grid(N/64 [j], C/64 [c]), block 256, per-thread 4c x 4j, K-chunk 32.
#define TC 64
#define TJ 64
#define KI 32
__global__ __launch_bounds__(256) void attn_out_kernel(
    const float* __restrict__ hv, const float* __restrict__ se,
    const float* __restrict__ csum, const float* __restrict__ x,
    const float* __restrict__ gamma, float* __restrict__ out)
{
    __shared__ float hA[KI][TC + 4];   // [i][c], pad keeps float4 alignment (68*4=272B)
    __shared__ float hB[KI][TJ + 4];   // [i][j]
    int t  = threadIdx.x;
    int j0 = blockIdx.x * TJ;
    int c0 = blockIdx.y * TC;
    int tj = (t & 15) * 4;
    int tc = (t >> 4) * 4;

    float acc[4][4];
#pragma unroll
    for (int a = 0; a < 4; ++a)
#pragma unroll
        for (int b = 0; b < 4; ++b) acc[a][b] = 0.f;

    int ii  = t & 31, ccb = t >> 5;   // hv staging map
    int jj  = t & 63, irb = t >> 6;   // se staging map

    for (int i0 = 0; i0 < N_; i0 += KI) {
#pragma unroll
        for (int p = 0; p < TC / 8; ++p) {
            int cc = ccb + p * 8;
            hA[ii][cc] = hv[(size_t)(c0 + cc) * N_ + i0 + ii];
        }
#pragma unroll
        for (int p = 0; p < KI / 4; ++p) {
            int ir = irb + p * 4;
            hB[ir][jj] = se[(size_t)(i0 + ir) * N_ + j0 + jj];
        }
        __syncthreads();
#pragma unroll
        for (int k = 0; k < KI; ++k) {
            float4 av = *(const float4*)&hA[k][tc];
            float4 bv = *(const float4*)&hB[k][tj];
            acc[0][0] += av.x * bv.x; acc[0][1] += av.x * bv.y;
            acc[0][2] += av.x * bv.z; acc[0][3] += av.x * bv.w;
            acc[1][0] += av.y * bv.x; acc[1][1] += av.y * bv.y;
            acc[1][2] += av.y * bv.z; acc[1][3] += av.y * bv.w;
            acc[2][0] += av.z * bv.x; acc[2][1] += av.z * bv.y;
            acc[2][2] += av.z * bv.z; acc[2][3] += av.z * bv.w;
            acc[3][0] += av.w * bv.x; acc[3][1] += av.w * bv.y;
            acc[3][2] += av.w * bv.z; acc[3][3] += av.w * bv.w;
        }
        __syncthreads();
    }

    float gm = gamma[0];
    float4 sv = *(const float4*)&csum[j0 + tj];
    float4 inv;
    inv.x = 1.f / sv.x; inv.y = 1.f / sv.y; inv.z = 1.f / sv.z; inv.w = 1.f / sv.w;
#pragma unroll
    for (int ci = 0; ci < 4; ++ci) {
        int c = c0 + tc + ci;
        const float4 xv = *(const float4*)&x[(size_t)c * N_ + j0 + tj];
        float4 ov;
        ov.x = gm * acc[ci][0] * inv.x + xv.x;
        ov.y = gm * acc[ci][1] * inv.y + xv.y;
        ov.z = gm * acc[ci][2] * inv.z + xv.z;
        ov.w = gm * acc[ci][3] * inv.w + xv.w;
        *(float4*)&out[(size_t)c * N_ + j0 + tj] = ov;
    }
}

extern "C" void kernel_launch(void* const* d_in, const int* in_sizes, int n_in,
                              void* d_out, int out_size, void* d_ws, size_t ws_size,
                              hipStream_t stream) {
    const float* x     = (const float*)d_in[0];
    const float* Wq    = (const float*)d_in[1];
    const float* Wk    = (const float*)d_in[2];
    const float* Wv    = (const float*)d_in[3];
    const float* gamma = (const float*)d_in[4];
    float* out = (float*)d_out;

    float* ws   = (float*)d_ws;
    float* f    = ws;                                  //  4*32*4096
    float* g    = f    + (size_t)B_ * C8_ * N_;        //  4*32*4096
    float* hv   = g    + (size_t)B_ * C8_ * N_;        //  4*256*4096
    float* cmax = hv   + (size_t)B_ * C_  * N_;        //  4096
    float* csum = cmax + N_;                           //  4096
    float* sc   = csum + N_;                           //  4096*4096 (reused per batch)
    // total ~88 MB of ws

    proj_kernel<<<dim3(N_ / 256, C8_ / 16, B_), 256, 0, stream>>>(Wq, x, f,  C8_);
    proj_kernel<<<dim3(N_ / 256, C8_ / 16, B_), 256, 0, stream>>>(Wk, x, g,  C8_);
    proj_kernel<<<dim3(N_ / 256, C_  / 16, B_), 256, 0, stream>>>(Wv, x, hv, C_);

    for (int b = 0; b < B_; ++b) {
        const float* fb  = f  + (size_t)b * C8_ * N_;
        const float* gb  = g  + (size_t)b * C8_ * N_;
        const float* hvb = hv + (size_t)b * C_  * N_;
        const float* xb  = x  + (size_t)b * C_  * N_;
        float*       ob  = out + (size_t)b * C_ * N_;

        scores_kernel<<<dim3(N_ / 256, N_ / 16), 256, 0, stream>>>(fb, gb, sc);
        colmax_kernel<<<dim3(N_ / 64), 256, 0, stream>>>(sc, cmax);
        expsum_kernel<<<dim3(N_ / 64), 256, 0, stream>>>(sc, cmax, csum);
        attn_out_kernel<<<dim3(N_ / TJ, C_ / TC), 256, 0, stream>>>(
            hvb, sc, csum, xb, gamma, ob);
    }
}

// Round 2
// 781.648 us; speedup vs baseline: 3.6908x; 3.6908x over previous
//
#include <hip/hip_runtime.h>

#define B_  4
#define C_  256
#define C8_ 32
#define N_  4096   // H*W

#define TJ 128     // j-tile per block
#define KI 32      // i-tile per iteration
#define SPLITS 4   // i-range splits (for occupancy)

// ---------------- projections (unchanged from R1) ----------------
__global__ __launch_bounds__(256) void proj_kernel(
    const float* __restrict__ W, const float* __restrict__ x,
    float* __restrict__ y, int outC)
{
    int n  = blockIdx.x * 256 + threadIdx.x;
    int o0 = blockIdx.y * 16;
    int b  = blockIdx.z;
    const float* xb = x + (size_t)b * C_ * N_;
    float acc[16];
#pragma unroll
    for (int k = 0; k < 16; ++k) acc[k] = 0.f;
    for (int c = 0; c < C_; ++c) {
        float xv = xb[c * N_ + n];
#pragma unroll
        for (int k = 0; k < 16; ++k)
            acc[k] += W[(o0 + k) * C_ + c] * xv;
    }
#pragma unroll
    for (int k = 0; k < 16; ++k)
        y[((size_t)b * outC + o0 + k) * N_ + n] = acc[k];
}

// ---------------- fused flash attention ----------------
// Per block: queries j0..j0+127 (all 256 channels), i-range [s*1024,(s+1)*1024).
// No running max (scores bounded, fp32 exp safe): o,l are plain sums -> splittable.
// Thread PV tile: 16 c x 8 j. Score phase: 1 j x 16 i per thread, g in registers.
__global__ __launch_bounds__(256, 2) void flash_kernel(
    const float* __restrict__ f, const float* __restrict__ g,
    const float* __restrict__ hv, float* __restrict__ o_part,
    float* __restrict__ l_part)
{
    __shared__ float fT[KI][36];       // [i][ch]   (36: 16B-aligned rows, pad)
    __shared__ float hvT[KI][260];     // [i][c]    (260 = 4 mod 32 -> 4-way write conflict only)
    __shared__ float pL[KI][132];      // [i][j]    (132 = 16B-aligned rows)

    int t  = threadIdx.x;
    int b  = blockIdx.z;
    int s  = blockIdx.y;
    int j0 = blockIdx.x * TJ;

    const float* fb = f  + (size_t)b * C8_ * N_;
    const float* gb = g  + (size_t)b * C8_ * N_;
    const float* hb = hv + (size_t)b * C_  * N_;

    // score-phase mapping: thread scores column j=js for 16 i's
    int js    = t & 127;
    int ihalf = t >> 7;
    float g_reg[32];
#pragma unroll
    for (int ch = 0; ch < 32; ++ch)
        g_reg[ch] = gb[ch * N_ + j0 + js];

    // PV mapping: 16 c x 8 j per thread
    int tj = (t & 15) * 8;
    int tc = (t >> 4) * 16;

    float acc[16][8];
#pragma unroll
    for (int a = 0; a < 16; ++a)
#pragma unroll
        for (int q = 0; q < 8; ++q) acc[a][q] = 0.f;
    float lacc[8];
#pragma unroll
    for (int q = 0; q < 8; ++q) lacc[q] = 0.f;

    // staging maps
    int ii  = t & 31;
    int chg = (t >> 5) * 4;   // fT: 4 ch rows per thread
    int cg  = t >> 5;         // hvT: c = cg + 8*q

    int i_begin = s * (N_ / SPLITS);
    int i_end   = i_begin + N_ / SPLITS;

    for (int i0 = i_begin; i0 < i_end; i0 += KI) {
        __syncthreads();   // prior tile's PV reads done
        // ---- stage f tile ----
        float freg[4];
#pragma unroll
        for (int q = 0; q < 4; ++q)
            freg[q] = fb[(chg + q) * N_ + i0 + ii];
#pragma unroll
        for (int q = 0; q < 4; ++q)
            fT[ii][chg + q] = freg[q];
        // ---- stage hv tile ----
        float hreg[32];
#pragma unroll
        for (int q = 0; q < 32; ++q)
            hreg[q] = hb[(size_t)(cg + 8 * q) * N_ + i0 + ii];
#pragma unroll
        for (int q = 0; q < 32; ++q)
            hvT[ii][cg + 8 * q] = hreg[q];
        __syncthreads();   // staging visible

        // ---- scores + exp -> pL ----
#pragma unroll
        for (int it = 0; it < 16; ++it) {
            int i = ihalf * 16 + it;
            const float4* fr = (const float4*)&fT[i][0];
            float sum = 0.f;
#pragma unroll
            for (int q = 0; q < 8; ++q) {
                float4 fv = fr[q];
                sum += g_reg[q*4+0] * fv.x + g_reg[q*4+1] * fv.y
                     + g_reg[q*4+2] * fv.z + g_reg[q*4+3] * fv.w;
            }
            pL[i][js] = __expf(sum);
        }
        __syncthreads();   // pL visible

        // ---- PV accumulate ----
        for (int i = 0; i < KI; ++i) {
            float pj[8];
            *(float4*)&pj[0] = *(const float4*)&pL[i][tj];
            *(float4*)&pj[4] = *(const float4*)&pL[i][tj + 4];
#pragma unroll
            for (int q = 0; q < 8; ++q) lacc[q] += pj[q];
            float hc[16];
#pragma unroll
            for (int q = 0; q < 4; ++q)
                *(float4*)&hc[q * 4] = *(const float4*)&hvT[i][tc + q * 4];
#pragma unroll
            for (int cc = 0; cc < 16; ++cc)
#pragma unroll
                for (int jj = 0; jj < 8; ++jj)
                    acc[cc][jj] += hc[cc] * pj[jj];
        }
    }

    // ---- write partials ----
    float* ob = o_part + (size_t)(b * SPLITS + s) * C_ * N_;
#pragma unroll
    for (int cc = 0; cc < 16; ++cc) {
        int c = tc + cc;
        *(float4*)&ob[(size_t)c * N_ + j0 + tj]     = *(float4*)&acc[cc][0];
        *(float4*)&ob[(size_t)c * N_ + j0 + tj + 4] = *(float4*)&acc[cc][4];
    }
    if ((t >> 4) == 0) {
        float* lb = l_part + (size_t)(b * SPLITS + s) * N_;
        *(float4*)&lb[j0 + tj]     = *(float4*)&lacc[0];
        *(float4*)&lb[j0 + tj + 4] = *(float4*)&lacc[4];
    }
}

// ---------------- combine: sum splits, normalize, residual ----------------
__global__ __launch_bounds__(256) void combine_kernel(
    const float* __restrict__ o_part, const float* __restrict__ l_part,
    const float* __restrict__ x, const float* __restrict__ gamma,
    float* __restrict__ out)
{
    int j = blockIdx.x * 256 + threadIdx.x;
    int c = blockIdx.y;
    int b = blockIdx.z;
    float l = 0.f;
#pragma unroll
    for (int s = 0; s < SPLITS; ++s)
        l += l_part[(size_t)(b * SPLITS + s) * N_ + j];
    float o = 0.f;
#pragma unroll
    for (int s = 0; s < SPLITS; ++s)
        o += o_part[((size_t)(b * SPLITS + s) * C_ + c) * N_ + j];
    size_t idx = ((size_t)b * C_ + c) * N_ + j;
    out[idx] = gamma[0] * o / l + x[idx];
}

extern "C" void kernel_launch(void* const* d_in, const int* in_sizes, int n_in,
                              void* d_out, int out_size, void* d_ws, size_t ws_size,
                              hipStream_t stream) {
    const float* x     = (const float*)d_in[0];
    const float* Wq    = (const float*)d_in[1];
    const float* Wk    = (const float*)d_in[2];
    const float* Wv    = (const float*)d_in[3];
    const float* gamma = (const float*)d_in[4];
    float* out = (float*)d_out;

    float* ws     = (float*)d_ws;
    float* f      = ws;                                   // 4*32*4096   = 2 MB
    float* g      = f      + (size_t)B_ * C8_ * N_;       // 2 MB
    float* hv     = g      + (size_t)B_ * C8_ * N_;       // 16 MB
    float* o_part = hv     + (size_t)B_ * C_  * N_;       // 4*4*256*4096 = 64 MB
    float* l_part = o_part + (size_t)B_ * SPLITS * C_ * N_; // 256 KB

    proj_kernel<<<dim3(N_ / 256, C8_ / 16, B_), 256, 0, stream>>>(Wq, x, f,  C8_);
    proj_kernel<<<dim3(N_ / 256, C8_ / 16, B_), 256, 0, stream>>>(Wk, x, g,  C8_);
    proj_kernel<<<dim3(N_ / 256, C_  / 16, B_), 256, 0, stream>>>(Wv, x, hv, C_);

    flash_kernel<<<dim3(N_ / TJ, SPLITS, B_), 256, 0, stream>>>(f, g, hv, o_part, l_part);

    combine_kernel<<<dim3(N_ / 256, C_, B_), 256, 0, stream>>>(o_part, l_part, x, gamma, out);
}

// Round 3
// 294.281 us; speedup vs baseline: 9.8032x; 2.6561x over previous
//
#include <hip/hip_runtime.h>

#define B_  4
#define C_  256
#define C8_ 32
#define N_  4096   // H*W

#define TJ 128     // j-tile per flash block
#define KI 64      // i per iteration
#define SPLITS 4   // i-range splits

typedef __attribute__((ext_vector_type(8)))  short bf16x8;   // MFMA A/B frag (8 bf16)
typedef __attribute__((ext_vector_type(16))) float f32x16;   // MFMA C/D frag

union FragAB { bf16x8 v; unsigned short u[8]; };

__device__ __forceinline__ unsigned short f2bf(float x) {
    unsigned u = __float_as_uint(x);
    unsigned r = u + 0x7FFFu + ((u >> 16) & 1u);   // RNE
    return (unsigned short)(r >> 16);
}
__device__ __forceinline__ unsigned pack2bf(float a, float b) {
    return (unsigned)f2bf(a) | ((unsigned)f2bf(b) << 16);
}
__device__ __forceinline__ float bf2f(unsigned short h) {
    return __uint_as_float(((unsigned)h) << 16);
}

// ---------------- fused projection: f,g,hv (bf16 out) in one pass over x ---
// grid(N/64, B), 256 threads. xT holds the x tile bf16-packed: [n][c-pairs].
__global__ __launch_bounds__(256) void proj_all_kernel(
    const float* __restrict__ Wq, const float* __restrict__ Wk,
    const float* __restrict__ Wv, const float* __restrict__ x,
    unsigned short* __restrict__ f, unsigned short* __restrict__ g,
    unsigned short* __restrict__ hv)
{
    __shared__ unsigned xT[64][129];   // [n][cpair] as u32 (2 bf16); row 516B -> bank-stride 1: conflict-free
    int t  = threadIdx.x;
    int b  = blockIdx.y;
    int n0 = blockIdx.x * 64;
    int n  = t & 63;
    int og = t >> 6;                   // wave id -> wave-uniform W rows

    const float* xb = x + (size_t)b * C_ * N_;
    // stage x tile (bf16-packed pairs)
#pragma unroll
    for (int q = 0; q < 32; ++q) {
        int cp = og + 4 * q;           // c-pair index 0..127
        int c  = 2 * cp;
        float a0 = xb[(size_t)c * N_ + n0 + n];
        float a1 = xb[(size_t)(c + 1) * N_ + n0 + n];
        xT[n][cp] = pack2bf(a0, a1);
    }
    __syncthreads();

    for (int chunk = 0; chunk < 10; ++chunk) {
        int ocbase = chunk * 32 + og * 8;      // [0,320)
        const float* Wp; unsigned short* outp; int row; int outC;
        if (ocbase < 32)      { Wp = Wq; outp = f  + (size_t)b * C8_ * N_; row = ocbase;      outC = C8_; }
        else if (ocbase < 64) { Wp = Wk; outp = g  + (size_t)b * C8_ * N_; row = ocbase - 32; outC = C8_; }
        else                  { Wp = Wv; outp = hv + (size_t)b * C_  * N_; row = ocbase - 64; outC = C_;  }
        (void)outC;
        float acc[8];
#pragma unroll
        for (int q = 0; q < 8; ++q) acc[q] = 0.f;
        for (int cp = 0; cp < 128; ++cp) {
            unsigned u = xT[n][cp];
            float xlo = bf2f((unsigned short)(u & 0xffff));
            float xhi = bf2f((unsigned short)(u >> 16));
#pragma unroll
            for (int q = 0; q < 8; ++q) {
                acc[q] += Wp[(row + q) * C_ + 2 * cp]     * xlo;
                acc[q] += Wp[(row + q) * C_ + 2 * cp + 1] * xhi;
            }
        }
#pragma unroll
        for (int q = 0; q < 8; ++q)
            outp[(size_t)(row + q) * N_ + n0 + n] = f2bf(acc[q]);
    }
}

// ---------------- MFMA flash attention ----------------
// Block: j-tile 128, all 256 c, i-range N/SPLITS. 256 threads = 4 waves.
// Wave w: scores for j-quarter w; PV for c-range [w*64, w*64+64) x all 128 j.
// MFMA 32x32x16_bf16 layouts (m74/m101-verified):
//   A[m = lane&31][k = 8*(lane>>5) + r]
//   B[k = 8*(lane>>5) + r][n = lane&31]
//   C/D[row = (reg&3)+8*(reg>>2)+4*(lane>>5)][col = lane&31]
__global__ __launch_bounds__(256, 2) void flash_kernel(
    const unsigned short* __restrict__ f, const unsigned short* __restrict__ g,
    const unsigned short* __restrict__ hv, float* __restrict__ o_part,
    float* __restrict__ l_part)
{
    __shared__ unsigned short fT[64][40];     // [i][ch]  row 80B  (16B-aligned frags)
    __shared__ unsigned short hvT[256][72];   // [c][i]   row 144B
    __shared__ unsigned short pT[128][72];    // [j][i]   row 144B

    int t    = threadIdx.x;
    int w    = t >> 6;
    int lane = t & 63;
    int half = lane >> 5;
    int l31  = lane & 31;

    int b  = blockIdx.z;
    int s  = blockIdx.y;
    int j0 = blockIdx.x * TJ;

    const unsigned short* fb = f  + (size_t)b * C8_ * N_;
    const unsigned short* gb = g  + (size_t)b * C8_ * N_;
    const unsigned short* hb = hv + (size_t)b * C_  * N_;

    // ---- preload g B-frags for this wave's j-quarter (k = channel) ----
    FragAB gf[2];
#pragma unroll
    for (int ks = 0; ks < 2; ++ks)
#pragma unroll
        for (int r = 0; r < 8; ++r) {
            int ch = ks * 16 + half * 8 + r;
            gf[ks].u[r] = gb[(size_t)ch * N_ + j0 + w * 32 + l31];
        }

    f32x16 acc[8];   // [ct*4 + jt]
#pragma unroll
    for (int a = 0; a < 8; ++a) acc[a] = (f32x16)0.f;
    float lacc = 0.f;

    int i_begin = s * (N_ / SPLITS);
    int i_end   = i_begin + N_ / SPLITS;

    for (int i0 = i_begin; i0 < i_end; i0 += KI) {
        __syncthreads();   // previous PV reads of hvT/pT complete

        // ---- stage fT: [i][ch], 64 x 32 ----
        {
            int i   = t & 63;
            int chb = (t >> 6) * 8;
            unsigned short v[8];
#pragma unroll
            for (int q = 0; q < 8; ++q)
                v[q] = fb[(size_t)(chb + q) * N_ + i0 + i];
#pragma unroll
            for (int q = 0; q < 4; ++q)
                *(unsigned*)&fT[i][chb + 2 * q] =
                    (unsigned)v[2 * q] | ((unsigned)v[2 * q + 1] << 16);
        }
        // ---- stage hvT: [c][i], 256 x 64 ----
        {
            int crow  = t >> 3;
            int chunk = t & 7;
#pragma unroll
            for (int q = 0; q < 8; ++q) {
                int c = crow + 32 * q;
                uint4 v = *(const uint4*)&hb[(size_t)c * N_ + i0 + chunk * 8];
                *(uint4*)&hvT[c][chunk * 8] = v;
            }
        }
        __syncthreads();   // staging visible

        // ---- scores + exp -> pT (wave's j-quarter, both 32-i tiles) ----
#pragma unroll
        for (int it = 0; it < 2; ++it) {
            f32x16 sacc = (f32x16)0.f;
#pragma unroll
            for (int ks = 0; ks < 2; ++ks) {
                bf16x8 af = *(const bf16x8*)&fT[it * 32 + l31][ks * 16 + half * 8];
                sacc = __builtin_amdgcn_mfma_f32_32x32x16_bf16(af, gf[ks].v, sacc, 0, 0, 0);
            }
            float p[16];
#pragma unroll
            for (int r = 0; r < 16; ++r) {
                p[r] = __expf(sacc[r]);
                lacc += p[r];
            }
            int jr = w * 32 + l31;
#pragma unroll
            for (int a = 0; a < 4; ++a) {
                // rows i = it*32 + 8a + 4*half + {0..3}
                unsigned u0 = pack2bf(p[4 * a + 0], p[4 * a + 1]);
                unsigned u1 = pack2bf(p[4 * a + 2], p[4 * a + 3]);
                uint2 v; v.x = u0; v.y = u1;
                *(uint2*)&pT[jr][it * 32 + 8 * a + 4 * half] = v;
            }
        }
        __syncthreads();   // pT visible

        // ---- PV: acc[c-tile][j-tile] += hvT * pT ----
#pragma unroll
        for (int ks4 = 0; ks4 < 4; ++ks4) {
            int kofs = ks4 * 16 + half * 8;
            bf16x8 af[2], bf[4];
#pragma unroll
            for (int ct = 0; ct < 2; ++ct)
                af[ct] = *(const bf16x8*)&hvT[w * 64 + ct * 32 + l31][kofs];
#pragma unroll
            for (int jt = 0; jt < 4; ++jt)
                bf[jt] = *(const bf16x8*)&pT[jt * 32 + l31][kofs];
#pragma unroll
            for (int ct = 0; ct < 2; ++ct)
#pragma unroll
                for (int jt = 0; jt < 4; ++jt)
                    acc[ct * 4 + jt] = __builtin_amdgcn_mfma_f32_32x32x16_bf16(
                        af[ct], bf[jt], acc[ct * 4 + jt], 0, 0, 0);
        }
    }

    // ---- write partials ----
    float* ob = o_part + (size_t)(b * SPLITS + s) * C_ * N_;
#pragma unroll
    for (int ct = 0; ct < 2; ++ct)
#pragma unroll
        for (int jt = 0; jt < 4; ++jt) {
            f32x16 a = acc[ct * 4 + jt];
#pragma unroll
            for (int r = 0; r < 16; ++r) {
                int c = w * 64 + ct * 32 + (r & 3) + 8 * (r >> 2) + 4 * half;
                int j = j0 + jt * 32 + l31;
                ob[(size_t)c * N_ + j] = a[r];
            }
        }
    float lsum = lacc + __shfl_down(lacc, 32);
    if (lane < 32)
        l_part[(size_t)(b * SPLITS + s) * N_ + j0 + w * 32 + lane] = lsum;
}

// ---------------- combine: sum splits, normalize, residual ----------------
__global__ __launch_bounds__(256) void combine_kernel(
    const float* __restrict__ o_part, const float* __restrict__ l_part,
    const float* __restrict__ x, const float* __restrict__ gamma,
    float* __restrict__ out)
{
    int j = blockIdx.x * 256 + threadIdx.x;
    int b = blockIdx.z;
    float l = 0.f;
#pragma unroll
    for (int s = 0; s < SPLITS; ++s)
        l += l_part[(size_t)(b * SPLITS + s) * N_ + j];
    float inv = 1.f / l;
    float gm = gamma[0];
#pragma unroll
    for (int cc = 0; cc < 4; ++cc) {
        int c = blockIdx.y * 4 + cc;
        float o = 0.f;
#pragma unroll
        for (int s = 0; s < SPLITS; ++s)
            o += o_part[((size_t)(b * SPLITS + s) * C_ + c) * N_ + j];
        size_t idx = ((size_t)b * C_ + c) * N_ + j;
        out[idx] = gm * o * inv + x[idx];
    }
}

extern "C" void kernel_launch(void* const* d_in, const int* in_sizes, int n_in,
                              void* d_out, int out_size, void* d_ws, size_t ws_size,
                              hipStream_t stream) {
    const float* x     = (const float*)d_in[0];
    const float* Wq    = (const float*)d_in[1];
    const float* Wk    = (const float*)d_in[2];
    const float* Wv    = (const float*)d_in[3];
    const float* gamma = (const float*)d_in[4];
    float* out = (float*)d_out;

    char* ws = (char*)d_ws;
    float* o_part = (float*)ws;                                    // SPLITS*B*C*N*4 = 64 MB
    float* l_part = o_part + (size_t)SPLITS * B_ * C_ * N_;        // 256 KB
    unsigned short* f  = (unsigned short*)(l_part + (size_t)SPLITS * B_ * N_);
    unsigned short* g  = f + (size_t)B_ * C8_ * N_;                // 1 MB each
    unsigned short* hv = g + (size_t)B_ * C8_ * N_;                // 8 MB

    proj_all_kernel<<<dim3(N_ / 64, B_), 256, 0, stream>>>(Wq, Wk, Wv, x, f, g, hv);

    flash_kernel<<<dim3(N_ / TJ, SPLITS, B_), 256, 0, stream>>>(f, g, hv, o_part, l_part);

    combine_kernel<<<dim3(N_ / 256, C_ / 4, B_), 256, 0, stream>>>(o_part, l_part, x, gamma, out);
}

// Round 4
// 280.758 us; speedup vs baseline: 10.2753x; 1.0482x over previous
//
#include <hip/hip_runtime.h>

#define B_  4
#define C_  256
#define C8_ 32
#define N_  4096   // H*W

#define TJ 128     // j-tile per flash block
#define KI 64      // i per iteration
#define SPLITS 4   // i-range splits

typedef __attribute__((ext_vector_type(8)))  short bf16x8;   // MFMA A/B frag (8 bf16)
typedef __attribute__((ext_vector_type(16))) float f32x16;   // MFMA C/D frag

union FragAB { bf16x8 v; unsigned short u[8]; };

__device__ __forceinline__ unsigned short f2bf(float x) {
    unsigned u = __float_as_uint(x);
    unsigned r = u + 0x7FFFu + ((u >> 16) & 1u);   // RNE
    return (unsigned short)(r >> 16);
}
__device__ __forceinline__ unsigned pack2bf(float a, float b) {
    return (unsigned)f2bf(a) | ((unsigned)f2bf(b) << 16);
}

// ---------------- fused projection: f,g,hv (bf16 out), chunk-split ---------
// grid(N/64, 10, B), 256 threads. Block computes 32 out-channels for 64 n.
// xT: x tile bf16-packed [n][c-pair], row stride 132 u32 (528B, 16B-aligned).
__global__ __launch_bounds__(256) void proj_all_kernel(
    const float* __restrict__ Wq, const float* __restrict__ Wk,
    const float* __restrict__ Wv, const float* __restrict__ x,
    unsigned short* __restrict__ f, unsigned short* __restrict__ g,
    unsigned short* __restrict__ hv)
{
    __shared__ unsigned xT[64][132];
    int t     = threadIdx.x;
    int b     = blockIdx.z;
    int chunk = blockIdx.y;
    int n0    = blockIdx.x * 64;
    int n     = t & 63;
    int og    = t >> 6;

    const float* xb = x + (size_t)b * C_ * N_;
    // ---- stage x tile: thread packs c-pairs [og*32, og*32+32) for its n ----
#pragma unroll
    for (int q = 0; q < 8; ++q) {
        int cp0 = og * 32 + q * 4;
        uint4 v;
        v.x = pack2bf(xb[(size_t)(2*cp0+0)*N_ + n0+n], xb[(size_t)(2*cp0+1)*N_ + n0+n]);
        v.y = pack2bf(xb[(size_t)(2*cp0+2)*N_ + n0+n], xb[(size_t)(2*cp0+3)*N_ + n0+n]);
        v.z = pack2bf(xb[(size_t)(2*cp0+4)*N_ + n0+n], xb[(size_t)(2*cp0+5)*N_ + n0+n]);
        v.w = pack2bf(xb[(size_t)(2*cp0+6)*N_ + n0+n], xb[(size_t)(2*cp0+7)*N_ + n0+n]);
        *(uint4*)&xT[n][cp0] = v;
    }
    __syncthreads();

    int ocbase = chunk * 32 + og * 8;      // [0,320), same W matrix across block
    const float* Wp; unsigned short* outp; int row;
    if (ocbase < 32)      { Wp = Wq; outp = f  + (size_t)b * C8_ * N_; row = ocbase;      }
    else if (ocbase < 64) { Wp = Wk; outp = g  + (size_t)b * C8_ * N_; row = ocbase - 32; }
    else                  { Wp = Wv; outp = hv + (size_t)b * C_  * N_; row = ocbase - 64; }

    float acc[8];
#pragma unroll
    for (int r = 0; r < 8; ++r) acc[r] = 0.f;

    for (int q4 = 0; q4 < 32; ++q4) {
        uint4 u = *(const uint4*)&xT[n][q4 * 4];
        float xv[8];
        xv[0] = __uint_as_float(u.x << 16); xv[1] = __uint_as_float(u.x & 0xffff0000u);
        xv[2] = __uint_as_float(u.y << 16); xv[3] = __uint_as_float(u.y & 0xffff0000u);
        xv[4] = __uint_as_float(u.z << 16); xv[5] = __uint_as_float(u.z & 0xffff0000u);
        xv[6] = __uint_as_float(u.w << 16); xv[7] = __uint_as_float(u.w & 0xffff0000u);
        int cb = q4 * 8;
#pragma unroll
        for (int r = 0; r < 8; ++r)
#pragma unroll
            for (int cc = 0; cc < 8; ++cc)
                acc[r] += Wp[(size_t)(row + r) * C_ + cb + cc] * xv[cc];
    }
#pragma unroll
    for (int r = 0; r < 8; ++r)
        outp[(size_t)(row + r) * N_ + n0 + n] = f2bf(acc[r]);
}

// ---------------- MFMA flash attention (unchanged from R3) ----------------
// Block: j-tile 128, all 256 c, i-range N/SPLITS. 256 threads = 4 waves.
// MFMA 32x32x16_bf16 layouts (m74/m101-verified):
//   A[m = lane&31][k = 8*(lane>>5) + r]
//   B[k = 8*(lane>>5) + r][n = lane&31]
//   C/D[row = (reg&3)+8*(reg>>2)+4*(lane>>5)][col = lane&31]
__global__ __launch_bounds__(256, 2) void flash_kernel(
    const unsigned short* __restrict__ f, const unsigned short* __restrict__ g,
    const unsigned short* __restrict__ hv, float* __restrict__ o_part,
    float* __restrict__ l_part)
{
    __shared__ unsigned short fT[64][40];     // [i][ch]  row 80B
    __shared__ unsigned short hvT[256][72];   // [c][i]   row 144B
    __shared__ unsigned short pT[128][72];    // [j][i]   row 144B

    int t    = threadIdx.x;
    int w    = t >> 6;
    int lane = t & 63;
    int half = lane >> 5;
    int l31  = lane & 31;

    int b  = blockIdx.z;
    int s  = blockIdx.y;
    int j0 = blockIdx.x * TJ;

    const unsigned short* fb = f  + (size_t)b * C8_ * N_;
    const unsigned short* gb = g  + (size_t)b * C8_ * N_;
    const unsigned short* hb = hv + (size_t)b * C_  * N_;

    FragAB gf[2];
#pragma unroll
    for (int ks = 0; ks < 2; ++ks)
#pragma unroll
        for (int r = 0; r < 8; ++r) {
            int ch = ks * 16 + half * 8 + r;
            gf[ks].u[r] = gb[(size_t)ch * N_ + j0 + w * 32 + l31];
        }

    f32x16 acc[8];   // [ct*4 + jt]
#pragma unroll
    for (int a = 0; a < 8; ++a) acc[a] = (f32x16)0.f;
    float lacc = 0.f;

    int i_begin = s * (N_ / SPLITS);
    int i_end   = i_begin + N_ / SPLITS;

    for (int i0 = i_begin; i0 < i_end; i0 += KI) {
        __syncthreads();

        {   // stage fT: [i][ch], 64 x 32
            int i   = t & 63;
            int chb = (t >> 6) * 8;
            unsigned short v[8];
#pragma unroll
            for (int q = 0; q < 8; ++q)
                v[q] = fb[(size_t)(chb + q) * N_ + i0 + i];
#pragma unroll
            for (int q = 0; q < 4; ++q)
                *(unsigned*)&fT[i][chb + 2 * q] =
                    (unsigned)v[2 * q] | ((unsigned)v[2 * q + 1] << 16);
        }
        {   // stage hvT: [c][i], 256 x 64
            int crow  = t >> 3;
            int chunk = t & 7;
#pragma unroll
            for (int q = 0; q < 8; ++q) {
                int c = crow + 32 * q;
                uint4 v = *(const uint4*)&hb[(size_t)c * N_ + i0 + chunk * 8];
                *(uint4*)&hvT[c][chunk * 8] = v;
            }
        }
        __syncthreads();

        // scores + exp -> pT
#pragma unroll
        for (int it = 0; it < 2; ++it) {
            f32x16 sacc = (f32x16)0.f;
#pragma unroll
            for (int ks = 0; ks < 2; ++ks) {
                bf16x8 af = *(const bf16x8*)&fT[it * 32 + l31][ks * 16 + half * 8];
                sacc = __builtin_amdgcn_mfma_f32_32x32x16_bf16(af, gf[ks].v, sacc, 0, 0, 0);
            }
            float p[16];
#pragma unroll
            for (int r = 0; r < 16; ++r) {
                p[r] = __expf(sacc[r]);
                lacc += p[r];
            }
            int jr = w * 32 + l31;
#pragma unroll
            for (int a = 0; a < 4; ++a) {
                unsigned u0 = pack2bf(p[4 * a + 0], p[4 * a + 1]);
                unsigned u1 = pack2bf(p[4 * a + 2], p[4 * a + 3]);
                uint2 v; v.x = u0; v.y = u1;
                *(uint2*)&pT[jr][it * 32 + 8 * a + 4 * half] = v;
            }
        }
        __syncthreads();

        // PV accumulate
#pragma unroll
        for (int ks4 = 0; ks4 < 4; ++ks4) {
            int kofs = ks4 * 16 + half * 8;
            bf16x8 af[2], bf[4];
#pragma unroll
            for (int ct = 0; ct < 2; ++ct)
                af[ct] = *(const bf16x8*)&hvT[w * 64 + ct * 32 + l31][kofs];
#pragma unroll
            for (int jt = 0; jt < 4; ++jt)
                bf[jt] = *(const bf16x8*)&pT[jt * 32 + l31][kofs];
#pragma unroll
            for (int ct = 0; ct < 2; ++ct)
#pragma unroll
                for (int jt = 0; jt < 4; ++jt)
                    acc[ct * 4 + jt] = __builtin_amdgcn_mfma_f32_32x32x16_bf16(
                        af[ct], bf[jt], acc[ct * 4 + jt], 0, 0, 0);
        }
    }

    float* ob = o_part + (size_t)(b * SPLITS + s) * C_ * N_;
#pragma unroll
    for (int ct = 0; ct < 2; ++ct)
#pragma unroll
        for (int jt = 0; jt < 4; ++jt) {
            f32x16 a = acc[ct * 4 + jt];
#pragma unroll
            for (int r = 0; r < 16; ++r) {
                int c = w * 64 + ct * 32 + (r & 3) + 8 * (r >> 2) + 4 * half;
                int j = j0 + jt * 32 + l31;
                ob[(size_t)c * N_ + j] = a[r];
            }
        }
    float lsum = lacc + __shfl_down(lacc, 32);
    if (lane < 32)
        l_part[(size_t)(b * SPLITS + s) * N_ + j0 + w * 32 + lane] = lsum;
}

// ---------------- combine: sum splits, normalize, residual ----------------
__global__ __launch_bounds__(256) void combine_kernel(
    const float* __restrict__ o_part, const float* __restrict__ l_part,
    const float* __restrict__ x, const float* __restrict__ gamma,
    float* __restrict__ out)
{
    int j = blockIdx.x * 256 + threadIdx.x;
    int b = blockIdx.z;
    float l = 0.f;
#pragma unroll
    for (int s = 0; s < SPLITS; ++s)
        l += l_part[(size_t)(b * SPLITS + s) * N_ + j];
    float inv = 1.f / l;
    float gm = gamma[0];
#pragma unroll
    for (int cc = 0; cc < 4; ++cc) {
        int c = blockIdx.y * 4 + cc;
        float o = 0.f;
#pragma unroll
        for (int s = 0; s < SPLITS; ++s)
            o += o_part[((size_t)(b * SPLITS + s) * C_ + c) * N_ + j];
        size_t idx = ((size_t)b * C_ + c) * N_ + j;
        out[idx] = gm * o * inv + x[idx];
    }
}

extern "C" void kernel_launch(void* const* d_in, const int* in_sizes, int n_in,
                              void* d_out, int out_size, void* d_ws, size_t ws_size,
                              hipStream_t stream) {
    const float* x     = (const float*)d_in[0];
    const float* Wq    = (const float*)d_in[1];
    const float* Wk    = (const float*)d_in[2];
    const float* Wv    = (const float*)d_in[3];
    const float* gamma = (const float*)d_in[4];
    float* out = (float*)d_out;

    char* ws = (char*)d_ws;
    float* o_part = (float*)ws;                                    // 64 MB
    float* l_part = o_part + (size_t)SPLITS * B_ * C_ * N_;        // 256 KB
    unsigned short* f  = (unsigned short*)(l_part + (size_t)SPLITS * B_ * N_);
    unsigned short* g  = f + (size_t)B_ * C8_ * N_;                // 1 MB each
    unsigned short* hv = g + (size_t)B_ * C8_ * N_;                // 8 MB

    proj_all_kernel<<<dim3(N_ / 64, 10, B_), 256, 0, stream>>>(Wq, Wk, Wv, x, f, g, hv);

    flash_kernel<<<dim3(N_ / TJ, SPLITS, B_), 256, 0, stream>>>(f, g, hv, o_part, l_part);

    combine_kernel<<<dim3(N_ / 256, C_ / 4, B_), 256, 0, stream>>>(o_part, l_part, x, gamma, out);
}

// Round 5
// 158.789 us; speedup vs baseline: 18.1680x; 1.7681x over previous
//
#include <hip/hip_runtime.h>

#define B_  4
#define C_  256
#define C8_ 32
#define N_  4096   // H*W

#define TJ 128     // j-tile per flash block
#define KI 64      // i per iteration
#define SPLITS 4   // i-range splits

typedef __attribute__((ext_vector_type(8)))  short bf16x8;   // MFMA A/B frag (8 bf16)
typedef __attribute__((ext_vector_type(16))) float f32x16;   // MFMA C/D frag

union FragAB { bf16x8 v; unsigned short u[8]; };

__device__ __forceinline__ unsigned short f2bf(float x) {
    unsigned u = __float_as_uint(x);
    unsigned r = u + 0x7FFFu + ((u >> 16) & 1u);   // RNE
    return (unsigned short)(r >> 16);
}
__device__ __forceinline__ unsigned pack2bf(float a, float b) {
    return (unsigned)f2bf(a) | ((unsigned)f2bf(b) << 16);
}

// ---------------- prep: W concat -> bf16 [320][256] ----------------
__global__ __launch_bounds__(256) void prep_w_kernel(
    const float* __restrict__ Wq, const float* __restrict__ Wk,
    const float* __restrict__ Wv, unsigned short* __restrict__ Wbf)
{
    int idx = (blockIdx.x * 256 + threadIdx.x) * 4;   // grid 80 -> 81920 elems
    int row = idx >> 8;
    int col = idx & 255;
    const float* src; int r;
    if (row < 32)      { src = Wq; r = row;      }
    else if (row < 64) { src = Wk; r = row - 32; }
    else               { src = Wv; r = row - 64; }
    float4 v = *(const float4*)&src[r * 256 + col];
    uint2 o; o.x = pack2bf(v.x, v.y); o.y = pack2bf(v.z, v.w);
    *(uint2*)&Wbf[idx] = o;
}

// ---------------- prep: x [b][c][n] fp32 -> xT [b][n][c] bf16 ----------------
// grid(N/64, C/64, B), 256 threads, 64x64 tile via LDS.
__global__ __launch_bounds__(256) void prep_x_kernel(
    const float* __restrict__ x, unsigned short* __restrict__ xT)
{
    __shared__ unsigned short T[64][66];   // stride 66: bank = (33n + c/2)%32, conflict-free
    int t  = threadIdx.x;
    int b  = blockIdx.z;
    int c0 = blockIdx.y * 64;
    int n0 = blockIdx.x * 64;
    const float* xb = x + (size_t)b * C_ * N_;
    int n_l = t & 63, c_l = t >> 6;
#pragma unroll
    for (int q = 0; q < 16; ++q) {
        int c = c_l * 16 + q;
        T[n_l][c] = f2bf(xb[(size_t)(c0 + c) * N_ + n0 + n_l]);
    }
    __syncthreads();
    unsigned short* xTb = xT + (size_t)b * N_ * C_;
    int c_l2 = t & 63, nb = t >> 6;
#pragma unroll
    for (int q = 0; q < 16; ++q) {
        int n = nb * 16 + q;
        xTb[(size_t)(n0 + n) * C_ + c0 + c_l2] = T[n][c_l2];
    }
}

// ---------------- MFMA projection: [320x256] x [256 x 32n] per block -------
// grid(N/32, B), 256 threads = 4 waves. Wave w: m-tiles {w, w+4, w+8(w<2)}.
// No LDS: A/B frags loaded directly from global (Wbf L2-resident, xT tile 16KB).
// MFMA 32x32x16_bf16: A[m=lane&31][k=8*half+r], B[k=8*half+r][n=lane&31],
//                     D[row=(r&3)+8*(r>>2)+4*half][col=lane&31]
__global__ __launch_bounds__(256) void proj_mfma_kernel(
    const unsigned short* __restrict__ Wbf, const unsigned short* __restrict__ xT,
    unsigned short* __restrict__ f, unsigned short* __restrict__ g,
    unsigned short* __restrict__ hv)
{
    int t = threadIdx.x, w = t >> 6, lane = t & 63;
    int half = lane >> 5, l31 = lane & 31;
    int b  = blockIdx.y;
    int n0 = blockIdx.x * 32;

    const unsigned short* xb = xT + ((size_t)b * N_ + n0 + l31) * C_;
    int nm = (w < 2) ? 3 : 2;
    int mt0 = w, mt1 = w + 4, mt2 = w + 8;

    f32x16 acc[3];
#pragma unroll
    for (int a = 0; a < 3; ++a) acc[a] = (f32x16)0.f;

#pragma unroll
    for (int ks = 0; ks < 16; ++ks) {
        int kofs = ks * 16 + half * 8;
        bf16x8 bfr = *(const bf16x8*)&xb[kofs];
        bf16x8 a0 = *(const bf16x8*)&Wbf[(size_t)(mt0 * 32 + l31) * 256 + kofs];
        acc[0] = __builtin_amdgcn_mfma_f32_32x32x16_bf16(a0, bfr, acc[0], 0, 0, 0);
        bf16x8 a1 = *(const bf16x8*)&Wbf[(size_t)(mt1 * 32 + l31) * 256 + kofs];
        acc[1] = __builtin_amdgcn_mfma_f32_32x32x16_bf16(a1, bfr, acc[1], 0, 0, 0);
        if (nm == 3) {
            bf16x8 a2 = *(const bf16x8*)&Wbf[(size_t)(mt2 * 32 + l31) * 256 + kofs];
            acc[2] = __builtin_amdgcn_mfma_f32_32x32x16_bf16(a2, bfr, acc[2], 0, 0, 0);
        }
    }

    unsigned short* fb = f  + (size_t)b * C8_ * N_;
    unsigned short* gb = g  + (size_t)b * C8_ * N_;
    unsigned short* hb = hv + (size_t)b * C_  * N_;
#pragma unroll
    for (int im = 0; im < 3; ++im) {
        if (im >= nm) break;
        int mt = (im == 0) ? mt0 : (im == 1) ? mt1 : mt2;
#pragma unroll
        for (int r = 0; r < 16; ++r) {
            int R = mt * 32 + (r & 3) + 8 * (r >> 2) + 4 * half;
            unsigned short v = f2bf(acc[im][r]);
            if (R < 32)       fb[(size_t)R * N_ + n0 + l31] = v;
            else if (R < 64)  gb[(size_t)(R - 64 + 32) * N_ + n0 + l31] = v;
            else              hb[(size_t)(R - 64) * N_ + n0 + l31] = v;
        }
    }
}

// ---------------- MFMA flash attention (unchanged from R3) ----------------
__global__ __launch_bounds__(256, 2) void flash_kernel(
    const unsigned short* __restrict__ f, const unsigned short* __restrict__ g,
    const unsigned short* __restrict__ hv, float* __restrict__ o_part,
    float* __restrict__ l_part)
{
    __shared__ unsigned short fT[64][40];     // [i][ch]  row 80B
    __shared__ unsigned short hvT[256][72];   // [c][i]   row 144B
    __shared__ unsigned short pT[128][72];    // [j][i]   row 144B

    int t    = threadIdx.x;
    int w    = t >> 6;
    int lane = t & 63;
    int half = lane >> 5;
    int l31  = lane & 31;

    int b  = blockIdx.z;
    int s  = blockIdx.y;
    int j0 = blockIdx.x * TJ;

    const unsigned short* fb = f  + (size_t)b * C8_ * N_;
    const unsigned short* gb = g  + (size_t)b * C8_ * N_;
    const unsigned short* hb = hv + (size_t)b * C_  * N_;

    FragAB gf[2];
#pragma unroll
    for (int ks = 0; ks < 2; ++ks)
#pragma unroll
        for (int r = 0; r < 8; ++r) {
            int ch = ks * 16 + half * 8 + r;
            gf[ks].u[r] = gb[(size_t)ch * N_ + j0 + w * 32 + l31];
        }

    f32x16 acc[8];   // [ct*4 + jt]
#pragma unroll
    for (int a = 0; a < 8; ++a) acc[a] = (f32x16)0.f;
    float lacc = 0.f;

    int i_begin = s * (N_ / SPLITS);
    int i_end   = i_begin + N_ / SPLITS;

    for (int i0 = i_begin; i0 < i_end; i0 += KI) {
        __syncthreads();

        {   // stage fT: [i][ch], 64 x 32
            int i   = t & 63;
            int chb = (t >> 6) * 8;
            unsigned short v[8];
#pragma unroll
            for (int q = 0; q < 8; ++q)
                v[q] = fb[(size_t)(chb + q) * N_ + i0 + i];
#pragma unroll
            for (int q = 0; q < 4; ++q)
                *(unsigned*)&fT[i][chb + 2 * q] =
                    (unsigned)v[2 * q] | ((unsigned)v[2 * q + 1] << 16);
        }
        {   // stage hvT: [c][i], 256 x 64
            int crow  = t >> 3;
            int chunk = t & 7;
#pragma unroll
            for (int q = 0; q < 8; ++q) {
                int c = crow + 32 * q;
                uint4 v = *(const uint4*)&hb[(size_t)c * N_ + i0 + chunk * 8];
                *(uint4*)&hvT[c][chunk * 8] = v;
            }
        }
        __syncthreads();

        // scores + exp -> pT
#pragma unroll
        for (int it = 0; it < 2; ++it) {
            f32x16 sacc = (f32x16)0.f;
#pragma unroll
            for (int ks = 0; ks < 2; ++ks) {
                bf16x8 af = *(const bf16x8*)&fT[it * 32 + l31][ks * 16 + half * 8];
                sacc = __builtin_amdgcn_mfma_f32_32x32x16_bf16(af, gf[ks].v, sacc, 0, 0, 0);
            }
            float p[16];
#pragma unroll
            for (int r = 0; r < 16; ++r) {
                p[r] = __expf(sacc[r]);
                lacc += p[r];
            }
            int jr = w * 32 + l31;
#pragma unroll
            for (int a = 0; a < 4; ++a) {
                unsigned u0 = pack2bf(p[4 * a + 0], p[4 * a + 1]);
                unsigned u1 = pack2bf(p[4 * a + 2], p[4 * a + 3]);
                uint2 v; v.x = u0; v.y = u1;
                *(uint2*)&pT[jr][it * 32 + 8 * a + 4 * half] = v;
            }
        }
        __syncthreads();

        // PV accumulate
#pragma unroll
        for (int ks4 = 0; ks4 < 4; ++ks4) {
            int kofs = ks4 * 16 + half * 8;
            bf16x8 af[2], bfr[4];
#pragma unroll
            for (int ct = 0; ct < 2; ++ct)
                af[ct] = *(const bf16x8*)&hvT[w * 64 + ct * 32 + l31][kofs];
#pragma unroll
            for (int jt = 0; jt < 4; ++jt)
                bfr[jt] = *(const bf16x8*)&pT[jt * 32 + l31][kofs];
#pragma unroll
            for (int ct = 0; ct < 2; ++ct)
#pragma unroll
                for (int jt = 0; jt < 4; ++jt)
                    acc[ct * 4 + jt] = __builtin_amdgcn_mfma_f32_32x32x16_bf16(
                        af[ct], bfr[jt], acc[ct * 4 + jt], 0, 0, 0);
        }
    }

    float* ob = o_part + (size_t)(b * SPLITS + s) * C_ * N_;
#pragma unroll
    for (int ct = 0; ct < 2; ++ct)
#pragma unroll
        for (int jt = 0; jt < 4; ++jt) {
            f32x16 a = acc[ct * 4 + jt];
#pragma unroll
            for (int r = 0; r < 16; ++r) {
                int c = w * 64 + ct * 32 + (r & 3) + 8 * (r >> 2) + 4 * half;
                int j = j0 + jt * 32 + l31;
                ob[(size_t)c * N_ + j] = a[r];
            }
        }
    float lsum = lacc + __shfl_down(lacc, 32);
    if (lane < 32)
        l_part[(size_t)(b * SPLITS + s) * N_ + j0 + w * 32 + lane] = lsum;
}

// ---------------- combine: sum splits, normalize, residual ----------------
__global__ __launch_bounds__(256) void combine_kernel(
    const float* __restrict__ o_part, const float* __restrict__ l_part,
    const float* __restrict__ x, const float* __restrict__ gamma,
    float* __restrict__ out)
{
    int j = blockIdx.x * 256 + threadIdx.x;
    int b = blockIdx.z;
    float l = 0.f;
#pragma unroll
    for (int s = 0; s < SPLITS; ++s)
        l += l_part[(size_t)(b * SPLITS + s) * N_ + j];
    float inv = 1.f / l;
    float gm = gamma[0];
#pragma unroll
    for (int cc = 0; cc < 4; ++cc) {
        int c = blockIdx.y * 4 + cc;
        float o = 0.f;
#pragma unroll
        for (int s = 0; s < SPLITS; ++s)
            o += o_part[((size_t)(b * SPLITS + s) * C_ + c) * N_ + j];
        size_t idx = ((size_t)b * C_ + c) * N_ + j;
        out[idx] = gm * o * inv + x[idx];
    }
}

extern "C" void kernel_launch(void* const* d_in, const int* in_sizes, int n_in,
                              void* d_out, int out_size, void* d_ws, size_t ws_size,
                              hipStream_t stream) {
    const float* x     = (const float*)d_in[0];
    const float* Wq    = (const float*)d_in[1];
    const float* Wk    = (const float*)d_in[2];
    const float* Wv    = (const float*)d_in[3];
    const float* gamma = (const float*)d_in[4];
    float* out = (float*)d_out;

    char* ws = (char*)d_ws;
    float* o_part = (float*)ws;                                    // 64 MB
    float* l_part = o_part + (size_t)SPLITS * B_ * C_ * N_;        // 256 KB
    unsigned short* f   = (unsigned short*)(l_part + (size_t)SPLITS * B_ * N_);
    unsigned short* g   = f   + (size_t)B_ * C8_ * N_;             // 1 MB each
    unsigned short* hv  = g   + (size_t)B_ * C8_ * N_;             // 8 MB
    unsigned short* Wbf = hv  + (size_t)B_ * C_  * N_;             // 160 KB
    unsigned short* xT  = Wbf + (size_t)(C_ + 2 * C8_) * C_;       // 8.4 MB

    prep_w_kernel<<<dim3(80), 256, 0, stream>>>(Wq, Wk, Wv, Wbf);
    prep_x_kernel<<<dim3(N_ / 64, C_ / 64, B_), 256, 0, stream>>>(x, xT);

    proj_mfma_kernel<<<dim3(N_ / 32, B_), 256, 0, stream>>>(Wbf, xT, f, g, hv);

    flash_kernel<<<dim3(N_ / TJ, SPLITS, B_), 256, 0, stream>>>(f, g, hv, o_part, l_part);

    combine_kernel<<<dim3(N_ / 256, C_ / 4, B_), 256, 0, stream>>>(o_part, l_part, x, gamma, out);
}